// Round 10
// baseline (516.868 us; speedup 1.0000x reference)
//
#include <hip/hip_runtime.h>
#include <hip/hip_bf16.h>

typedef __bf16 bf16x8 __attribute__((ext_vector_type(8)));
typedef float f32x4 __attribute__((ext_vector_type(4)));
typedef __hip_bfloat16 bf16;

static constexpr int NN = 8192;
static constexpr int DD = 128;
static constexpr int KTOP = 1638;   // int(0.2 * 8192)
static constexpr int KSLICE = 4;    // split-K factor for the AV GEMM
static constexpr int KCH = NN / KSLICE;

// ---------------- input dtype detection ----------------
__global__ void detect_dtype(const unsigned short* __restrict__ xin, int* __restrict__ flag) {
  __shared__ int cnt;
  if (threadIdx.x == 0) cnt = 0;
  __syncthreads();
  int c = 0;
  for (int i = threadIdx.x; i < 4096; i += 256) {
    int e = (xin[i] >> 7) & 0xFF;
    if (e >= 0x8A) ++c;
  }
  atomicAdd(&cnt, c);
  __syncthreads();
  if (threadIdx.x == 0) *flag = (cnt > 16) ? 1 : 0;
}

// ---------------- merged prep: cvt x, cvt imp, transpose W (dual dtype) ----------------
__global__ void prep(const void* __restrict__ x_in, const void* __restrict__ imp_in,
                     const void* __restrict__ W1, const void* __restrict__ W2,
                     float* __restrict__ xf, float* __restrict__ impf,
                     bf16* __restrict__ Wt1, bf16* __restrict__ Wt2,
                     const int* __restrict__ flag) {
  int isf32 = *flag;
  int b = blockIdx.x;
  if (b < 4096) {
    int i = b * 256 + threadIdx.x;
    xf[i] = isf32 ? ((const float*)x_in)[i] : __bfloat162float(((const bf16*)x_in)[i]);
  } else if (b == 4096) {
    for (int i = threadIdx.x; i < NN; i += 256)
      impf[i] = isf32 ? ((const float*)imp_in)[i] : __bfloat162float(((const bf16*)imp_in)[i]);
  } else {
    int w = b - 4097;                 // 0,1 -> W1 l=0,1 ; 2,3 -> W2 l=0,1
    const void* srcv = (w < 2 ? W1 : W2);
    bf16* dst = (w < 2 ? Wt1 : Wt2) + (w & 1) * DD * DD;
    int off = (w & 1) * DD * DD;
    for (int f = threadIdx.x; f < DD * DD; f += 256) {
      int n = f >> 7, k = f & 127;
      float v = isf32 ? ((const float*)srcv)[off + k * DD + n]
                      : __bfloat162float(((const bf16*)srcv)[off + k * DD + n]);
      dst[n * DD + k] = __float2bfloat16(v);
    }
  }
}

// per-row L2 normalize -> xnb (bf16), plus plain bf16 cast -> xb
__global__ void rownorm(const float* __restrict__ xf, bf16* __restrict__ xnb, bf16* __restrict__ xb) {
  int wave = threadIdx.x >> 6;
  int lane = threadIdx.x & 63;
  int row = blockIdx.x * 4 + wave;
  const float* xr = xf + (long)row * DD;
  float2 v = reinterpret_cast<const float2*>(xr)[lane];
  float s = v.x * v.x + v.y * v.y;
  for (int off = 1; off < 64; off <<= 1) s += __shfl_xor(s, off);
  float inv = 1.0f / (sqrtf(s) + 1e-8f);
  int c = lane * 2;
  xb[(long)row * DD + c]      = __float2bfloat16(v.x);
  xb[(long)row * DD + c + 1]  = __float2bfloat16(v.y);
  xnb[(long)row * DD + c]     = __float2bfloat16(v.x * inv);
  xnb[(long)row * DD + c + 1] = __float2bfloat16(v.y * inv);
}

// ---------------- rank-5 factorized Gaussian prior ----------------
// P_ij = exp(-(di-dj)^2/32) = a_i a_j exp(di dj/16); 5-term Taylor of exp(z), z<=1/16.
__launch_bounds__(256)
__global__ void prior_reduce(const float* __restrict__ impf, const bf16* __restrict__ Yt1,
                             float* __restrict__ Mt, float* __restrict__ Gt) {
  __shared__ float red[5][4];
  int c = blockIdx.x;
  int tid = threadIdx.x;
  float s[5] = {0.f, 0.f, 0.f, 0.f, 0.f};
  bool hasY = (c < 128);
  const bf16* col = Yt1 + (long)(hasY ? c : 0) * NN;
  for (int j = tid; j < NN; j += 256) {
    float d = impf[j];
    float a = __expf(d * d * (-1.0f / 32.0f));
    float p = hasY ? a * __bfloat162float(col[j]) : a;
    #pragma unroll
    for (int t = 0; t < 5; ++t) { s[t] += p; p *= d; }
  }
  #pragma unroll
  for (int t = 0; t < 5; ++t)
    for (int off = 1; off < 64; off <<= 1) s[t] += __shfl_xor(s[t], off);
  int wave = tid >> 6, lane = tid & 63;
  if (lane == 0)
    #pragma unroll
    for (int t = 0; t < 5; ++t) red[t][wave] = s[t];
  __syncthreads();
  if (tid == 0) {
    #pragma unroll
    for (int t = 0; t < 5; ++t) {
      float v = red[t][0] + red[t][1] + red[t][2] + red[t][3];
      if (hasY) Mt[t * 128 + c] = v; else Gt[t] = v;
    }
  }
}

__global__ void prior_vec(const float* __restrict__ impf, const float* __restrict__ Gt,
                          float* __restrict__ pvec) {
  int i = blockIdx.x * 256 + threadIdx.x;
  float d = impf[i];
  float a = __expf(d * d * (-1.0f / 32.0f));
  const float ct[5] = {1.0f, 1.0f / 16.0f, 1.0f / 512.0f, 1.0f / 24576.0f, 1.0f / 1572864.0f};
  float g[5];
  float p = a;
  #pragma unroll
  for (int t = 0; t < 5; ++t) { g[t] = ct[t] * p; p *= d; }
  float rs = 1.0f;  // + eye
  #pragma unroll
  for (int t = 0; t < 5; ++t) rs += g[t] * Gt[t];
  float inv = 1.0f / rs;
  #pragma unroll
  for (int t = 0; t < 5; ++t) pvec[i * 8 + t] = g[t] * inv;
  pvec[i * 8 + 5] = inv;
}

// ---------------- K=128 GEMM (MFMA): C = A @ Bt^T ----------------
// transC: writes C[n][m] (ldc = NN). Cr (optional): row-major copy C[m][n], ld = DD.
__launch_bounds__(256)
__global__ void gemm_k128(const bf16* __restrict__ A, const bf16* __restrict__ Bt,
                          bf16* __restrict__ C, int ldc, int transC, bf16* __restrict__ Cr) {
  __shared__ bf16 lA[128][136];
  __shared__ bf16 lB[64][136];
  int tid = threadIdx.x;
  long rowA0 = (long)blockIdx.y * 128;
  long rowB0 = (long)blockIdx.x * 64;
  for (int i = 0; i < 8; ++i) {
    int f = tid + i * 256;
    int r = f >> 4, kg = f & 15;
    *reinterpret_cast<uint4*>(&lA[r][kg * 8]) =
        *reinterpret_cast<const uint4*>(A + (rowA0 + r) * DD + kg * 8);
  }
  for (int i = 0; i < 4; ++i) {
    int f = tid + i * 256;
    int r = f >> 4, kg = f & 15;
    *reinterpret_cast<uint4*>(&lB[r][kg * 8]) =
        *reinterpret_cast<const uint4*>(Bt + (rowB0 + r) * DD + kg * 8);
  }
  __syncthreads();
  int wave = tid >> 6, lane = tid & 63;
  int wm = (wave >> 1) * 64;
  int wn = (wave & 1) * 32;
  int quad = lane >> 4, l16 = lane & 15;
  f32x4 acc[4][2];
  #pragma unroll
  for (int mi = 0; mi < 4; ++mi)
    #pragma unroll
    for (int ni = 0; ni < 2; ++ni) acc[mi][ni] = {0.f, 0.f, 0.f, 0.f};
  #pragma unroll
  for (int ks = 0; ks < 4; ++ks) {
    int kb = ks * 32 + quad * 8;
    bf16x8 af[4], bfr[2];
    #pragma unroll
    for (int mi = 0; mi < 4; ++mi)
      af[mi] = *reinterpret_cast<const bf16x8*>(&lA[wm + mi * 16 + l16][kb]);
    #pragma unroll
    for (int ni = 0; ni < 2; ++ni)
      bfr[ni] = *reinterpret_cast<const bf16x8*>(&lB[wn + ni * 16 + l16][kb]);
    #pragma unroll
    for (int mi = 0; mi < 4; ++mi)
      #pragma unroll
      for (int ni = 0; ni < 2; ++ni)
        acc[mi][ni] = __builtin_amdgcn_mfma_f32_16x16x32_bf16(af[mi], bfr[ni], acc[mi][ni], 0, 0, 0);
  }
  #pragma unroll
  for (int mi = 0; mi < 4; ++mi)
    #pragma unroll
    for (int ni = 0; ni < 2; ++ni)
      #pragma unroll
      for (int r = 0; r < 4; ++r) {
        long row = rowA0 + wm + mi * 16 + quad * 4 + r;
        long col = rowB0 + wn + ni * 16 + l16;
        bf16 v = __float2bfloat16(acc[mi][ni][r]);
        if (transC) C[col * (long)ldc + row] = v;
        else        C[row * (long)ldc + col] = v;
        if (Cr)     Cr[row * DD + col] = v;
      }
}

// ---------------- per-row exact top-k threshold + rowsum ----------------
// Radix binary search on order-preserving u16 keys of bf16.
// 512 threads/row, 16 keys/thread so keys[] stays VGPR-resident (the 256-thread
// variant spilled 32 keys to AGPRs -> v_accvgpr_read per access, 2.7x VALU).
// Count per candidate: inline-asm v_cmp -> SGPR mask + scalar popcount; cross-
// wave combine via one ds_read + 3-step shfl_xor (every lane ends with total).
__launch_bounds__(512)
__global__ void topk_thresh(const bf16* __restrict__ S, unsigned short* __restrict__ kthr,
                            float* __restrict__ invRsF) {
  __shared__ int red[2][8];
  __shared__ float sred[8];
  int tid = threadIdx.x;
  int wave = tid >> 6, lane = tid & 63;
  long base = (long)blockIdx.x * NN;
  unsigned keys[16];
  #pragma unroll
  for (int i = 0; i < 2; ++i) {
    int f = tid + i * 512;
    uint4 v = *reinterpret_cast<const uint4*>(S + base + (long)f * 8);
    const unsigned short* p = reinterpret_cast<const unsigned short*>(&v);
    #pragma unroll
    for (int e = 0; e < 8; ++e) {
      unsigned short u = p[e];
      keys[i * 8 + e] = (u & 0x8000) ? (unsigned)(unsigned short)~u
                                     : (unsigned)(u | 0x8000);
    }
  }
  unsigned cur = 0;
  #pragma unroll
  for (int bit = 15; bit >= 0; --bit) {
    unsigned cand = cur | (1u << bit);
    int c = 0;
    #pragma unroll
    for (int i = 0; i < 16; ++i) {
      unsigned long long m;
      asm("v_cmp_ge_u32 %0, %1, %2" : "=s"(m) : "v"(keys[i]), "s"(cand));
      c += (int)__builtin_popcountll(m);
    }
    int buf = bit & 1;                 // double buffer -> one barrier per iteration
    if (lane == 0) red[buf][wave] = c; // c is wave-uniform
    __syncthreads();
    int t = red[buf][lane & 7];        // lanes read the 8 wave-counts (broadcast groups)
    t += __shfl_xor(t, 1);
    t += __shfl_xor(t, 2);
    t += __shfl_xor(t, 4);             // every lane now holds the block total
    if (t >= KTOP) cur = cand;
  }
  float sum = 0.f;
  #pragma unroll
  for (int i = 0; i < 16; ++i) {
    unsigned k = keys[i];
    if (k >= cur) {
      unsigned short u = (k & 0x8000u) ? (unsigned short)(k ^ 0x8000u) : (unsigned short)~k;
      sum += __uint_as_float(((unsigned int)u) << 16);
    }
  }
  for (int off = 1; off < 64; off <<= 1) sum += __shfl_xor(sum, off);
  if (lane == 0) sred[wave] = sum;
  __syncthreads();
  if (tid == 0) {
    float s = 0.f;
    #pragma unroll
    for (int w = 0; w < 8; ++w) s += sred[w];
    invRsF[blockIdx.x] = 1.0f / (s + 1.0f);
    kthr[blockIdx.x] = (unsigned short)cur;
  }
}

// ---------------- split-K masked AV GEMM: Pacc[s] = (mask(S) @ Y2) over k-slice s ----
__launch_bounds__(256)
__global__ void fused_av_partial(const bf16* __restrict__ S, const bf16* __restrict__ Yt2,
                                 const unsigned short* __restrict__ kthr,
                                 float* __restrict__ Pacc) {
  __shared__ bf16 lAf[32][72];
  __shared__ bf16 lY2[128][72];
  int tid = threadIdx.x;
  long row0 = (long)blockIdx.x * 32;
  long kbase = (long)blockIdx.y * KCH;
  int wave = tid >> 6, lane = tid & 63;
  int wm = (wave >> 1) * 16;   // 0 / 16
  int wn = (wave & 1) * 64;    // 0 / 64
  int quad = lane >> 4, l16 = lane & 15;
  int sr = tid >> 3, skg = tid & 7;          // staging coords: row, k-group
  int tk = kthr[row0 + sr];                  // per-thread row threshold key
  const bf16* srow = S + (row0 + sr) * (long)NN + kbase + skg * 8;
  f32x4 accF[4];
  #pragma unroll
  for (int ni = 0; ni < 4; ++ni) accF[ni] = {0.f, 0.f, 0.f, 0.f};
  for (int k0 = 0; k0 < KCH; k0 += 64) {
    __syncthreads();
    {
      uint4 v = *reinterpret_cast<const uint4*>(srow + k0);
      const unsigned short* p = reinterpret_cast<const unsigned short*>(&v);
      unsigned short m[8];
      #pragma unroll
      for (int e = 0; e < 8; ++e) {
        unsigned short u = p[e];
        int key = (u & 0x8000) ? (unsigned short)~u : (unsigned short)(u | 0x8000);
        m[e] = (key >= tk) ? u : (unsigned short)0;
      }
      *reinterpret_cast<uint4*>(&lAf[sr][skg * 8]) = *reinterpret_cast<const uint4*>(m);
    }
    for (int i = 0; i < 4; ++i) {       // 128 cols x 8 uint4
      int f = tid + i * 256;
      int c = f >> 3, kg = f & 7;
      *reinterpret_cast<uint4*>(&lY2[c][kg * 8]) =
          *reinterpret_cast<const uint4*>(Yt2 + (long)c * NN + kbase + k0 + kg * 8);
    }
    __syncthreads();
    #pragma unroll
    for (int ks = 0; ks < 2; ++ks) {
      int kb = ks * 32 + quad * 8;
      bf16x8 afm = *reinterpret_cast<const bf16x8*>(&lAf[wm + l16][kb]);
      #pragma unroll
      for (int ni = 0; ni < 4; ++ni) {
        bf16x8 b2 = *reinterpret_cast<const bf16x8*>(&lY2[wn + ni * 16 + l16][kb]);
        accF[ni] = __builtin_amdgcn_mfma_f32_16x16x32_bf16(afm, b2, accF[ni], 0, 0, 0);
      }
    }
  }
  float* out = Pacc + ((long)blockIdx.y * NN) * DD;
  #pragma unroll
  for (int ni = 0; ni < 4; ++ni)
    #pragma unroll
    for (int r = 0; r < 4; ++r) {
      long row = row0 + wm + quad * 4 + r;
      int col = wn + ni * 16 + l16;
      out[row * DD + col] = accF[ni][r];
    }
}

// ---------------- epilogue: reduce partials + prior + eye + leaky (+ optional final) ----
// If outf != nullptr: writes outf = v + hres*imp (final residual) instead of Xout.
__global__ void epilogue(const float* __restrict__ Pacc, const bf16* __restrict__ Yr1,
                         const bf16* __restrict__ Yr2, const float* __restrict__ pvec,
                         const float* __restrict__ Mt, const float* __restrict__ invRsF,
                         float* __restrict__ Xout, const float* __restrict__ hres,
                         const float* __restrict__ impf, float* __restrict__ outf) {
  int i = blockIdx.x * 256 + threadIdx.x;
  int row = i >> 7, col = i & 127;
  float acc = 0.f;
  #pragma unroll
  for (int s = 0; s < KSLICE; ++s) acc += Pacc[((long)s * NN + row) * DD + col];
  const float* pv = pvec + row * 8;
  float y1 = __bfloat162float(Yr1[i]);
  float y2 = __bfloat162float(Yr2[i]);
  float prior = pv[5] * y1 + pv[0] * Mt[col] + pv[1] * Mt[128 + col] + pv[2] * Mt[256 + col]
              + pv[3] * Mt[384 + col] + pv[4] * Mt[512 + col];
  float v = prior + invRsF[row] * (acc + y2);
  v = v > 0.f ? v : 0.01f * v;
  if (outf) outf[i] = v + hres[i] * impf[row];
  else      Xout[i] = v;
}

// ---------------- host ----------------

extern "C" void kernel_launch(void* const* d_in, const int* in_sizes, int n_in,
                              void* d_out, int out_size, void* d_ws, size_t ws_size,
                              hipStream_t stream) {
  const void* x_in   = d_in[0];
  const void* imp_in = d_in[1];
  const void* W1 = d_in[2];
  const void* W2 = d_in[3];
  float* out = (float*)d_out;

  char* ws = (char*)d_ws;
  size_t o = 0;
  auto alloc = [&](size_t bytes) { void* p = ws + o; o += (bytes + 511) & ~511ull; return p; };
  bf16*  Af   = (bf16*)alloc((size_t)NN * NN * 2);    // 134 MB raw similarity S
  float* Pacc = (float*)alloc((size_t)KSLICE * NN * DD * 4);  // 16 MB split-K partials
  float* xf0  = (float*)alloc((size_t)NN * DD * 4);
  float* xf1  = (float*)alloc((size_t)NN * DD * 4);
  bf16*  xnb  = (bf16*)alloc((size_t)NN * DD * 2);
  bf16*  xb   = (bf16*)alloc((size_t)NN * DD * 2);
  bf16*  Yt1  = (bf16*)alloc((size_t)NN * DD * 2);    // [128][8192] (x@W1)^T
  bf16*  Yt2  = (bf16*)alloc((size_t)NN * DD * 2);
  bf16*  Yr1  = (bf16*)alloc((size_t)NN * DD * 2);    // [8192][128] row-major copies
  bf16*  Yr2  = (bf16*)alloc((size_t)NN * DD * 2);
  bf16*  Wt1  = (bf16*)alloc((size_t)2 * DD * DD * 2);
  bf16*  Wt2  = (bf16*)alloc((size_t)2 * DD * DD * 2);
  float* impf = (float*)alloc((size_t)NN * 4);
  float* pvec = (float*)alloc((size_t)NN * 8 * 4);
  float* Mt   = (float*)alloc((size_t)5 * 128 * 4);
  float* Gt   = (float*)alloc((size_t)8 * 4);
  float* invRsF = (float*)alloc((size_t)NN * 4);
  unsigned short* kthr = (unsigned short*)alloc((size_t)NN * 2);
  int*   dflag  = (int*)alloc(64);
  (void)ws_size; (void)n_in; (void)in_sizes; (void)out_size;

  detect_dtype<<<1, 256, 0, stream>>>((const unsigned short*)x_in, dflag);
  prep<<<4101, 256, 0, stream>>>(x_in, imp_in, W1, W2, xf0, impf, Wt1, Wt2, dflag);

  float* xcur = xf0;
  for (int l = 0; l < 2; ++l) {
    float* xnxt = (l == 0) ? xf1 : xf0;
    rownorm<<<NN / 4, 256, 0, stream>>>(xcur, xnb, xb);
    gemm_k128<<<dim3(2, 64), 256, 0, stream>>>(xb, Wt1 + l * DD * DD, Yt1, NN, 1, Yr1);
    gemm_k128<<<dim3(2, 64), 256, 0, stream>>>(xb, Wt2 + l * DD * DD, Yt2, NN, 1, Yr2);
    prior_reduce<<<129, 256, 0, stream>>>(impf, Yt1, Mt, Gt);
    prior_vec<<<NN / 256, 256, 0, stream>>>(impf, Gt, pvec);
    gemm_k128<<<dim3(NN / 64, NN / 128), 256, 0, stream>>>(xnb, xnb, Af, NN, 0, nullptr);
    topk_thresh<<<NN, 512, 0, stream>>>(Af, kthr, invRsF);
    fused_av_partial<<<dim3(NN / 32, KSLICE), 256, 0, stream>>>(Af, Yt2, kthr, Pacc);
    if (l == 0)
      epilogue<<<NN * DD / 256, 256, 0, stream>>>(Pacc, Yr1, Yr2, pvec, Mt, invRsF,
                                                  xnxt, nullptr, nullptr, nullptr);
    else
      epilogue<<<NN * DD / 256, 256, 0, stream>>>(Pacc, Yr1, Yr2, pvec, Mt, invRsF,
                                                  nullptr, xf1, impf, out);
    xcur = xnxt;
  }
}

// Round 11
// 494.946 us; speedup vs baseline: 1.0443x; 1.0443x over previous
//
#include <hip/hip_runtime.h>
#include <hip/hip_bf16.h>

typedef __bf16 bf16x8 __attribute__((ext_vector_type(8)));
typedef float f32x4 __attribute__((ext_vector_type(4)));
typedef __hip_bfloat16 bf16;

static constexpr int NN = 8192;
static constexpr int DD = 128;
static constexpr int KTOP = 1638;   // int(0.2 * 8192)
static constexpr int KSLICE = 4;    // split-K factor for the AV GEMM
static constexpr int KCH = NN / KSLICE;

// ---------------- input dtype detection ----------------
__global__ void detect_dtype(const unsigned short* __restrict__ xin, int* __restrict__ flag) {
  __shared__ int cnt;
  if (threadIdx.x == 0) cnt = 0;
  __syncthreads();
  int c = 0;
  for (int i = threadIdx.x; i < 4096; i += 256) {
    int e = (xin[i] >> 7) & 0xFF;
    if (e >= 0x8A) ++c;
  }
  atomicAdd(&cnt, c);
  __syncthreads();
  if (threadIdx.x == 0) *flag = (cnt > 16) ? 1 : 0;
}

// ---------------- merged prep: cvt x, cvt imp, transpose W (dual dtype) ----------------
__global__ void prep(const void* __restrict__ x_in, const void* __restrict__ imp_in,
                     const void* __restrict__ W1, const void* __restrict__ W2,
                     float* __restrict__ xf, float* __restrict__ impf,
                     bf16* __restrict__ Wt1, bf16* __restrict__ Wt2,
                     const int* __restrict__ flag) {
  int isf32 = *flag;
  int b = blockIdx.x;
  if (b < 4096) {
    int i = b * 256 + threadIdx.x;
    xf[i] = isf32 ? ((const float*)x_in)[i] : __bfloat162float(((const bf16*)x_in)[i]);
  } else if (b == 4096) {
    for (int i = threadIdx.x; i < NN; i += 256)
      impf[i] = isf32 ? ((const float*)imp_in)[i] : __bfloat162float(((const bf16*)imp_in)[i]);
  } else {
    int w = b - 4097;                 // 0,1 -> W1 l=0,1 ; 2,3 -> W2 l=0,1
    const void* srcv = (w < 2 ? W1 : W2);
    bf16* dst = (w < 2 ? Wt1 : Wt2) + (w & 1) * DD * DD;
    int off = (w & 1) * DD * DD;
    for (int f = threadIdx.x; f < DD * DD; f += 256) {
      int n = f >> 7, k = f & 127;
      float v = isf32 ? ((const float*)srcv)[off + k * DD + n]
                      : __bfloat162float(((const bf16*)srcv)[off + k * DD + n]);
      dst[n * DD + k] = __float2bfloat16(v);
    }
  }
}

// per-row L2 normalize -> xnb (bf16), plus plain bf16 cast -> xb
__global__ void rownorm(const float* __restrict__ xf, bf16* __restrict__ xnb, bf16* __restrict__ xb) {
  int wave = threadIdx.x >> 6;
  int lane = threadIdx.x & 63;
  int row = blockIdx.x * 4 + wave;
  const float* xr = xf + (long)row * DD;
  float2 v = reinterpret_cast<const float2*>(xr)[lane];
  float s = v.x * v.x + v.y * v.y;
  for (int off = 1; off < 64; off <<= 1) s += __shfl_xor(s, off);
  float inv = 1.0f / (sqrtf(s) + 1e-8f);
  int c = lane * 2;
  xb[(long)row * DD + c]      = __float2bfloat16(v.x);
  xb[(long)row * DD + c + 1]  = __float2bfloat16(v.y);
  xnb[(long)row * DD + c]     = __float2bfloat16(v.x * inv);
  xnb[(long)row * DD + c + 1] = __float2bfloat16(v.y * inv);
}

// ---------------- rank-5 factorized Gaussian prior ----------------
// P_ij = exp(-(di-dj)^2/32) = a_i a_j exp(di dj/16); 5-term Taylor of exp(z), z<=1/16.
__launch_bounds__(256)
__global__ void prior_reduce(const float* __restrict__ impf, const bf16* __restrict__ Yt1,
                             float* __restrict__ Mt, float* __restrict__ Gt) {
  __shared__ float red[5][4];
  int c = blockIdx.x;
  int tid = threadIdx.x;
  float s[5] = {0.f, 0.f, 0.f, 0.f, 0.f};
  bool hasY = (c < 128);
  const bf16* col = Yt1 + (long)(hasY ? c : 0) * NN;
  for (int j = tid; j < NN; j += 256) {
    float d = impf[j];
    float a = __expf(d * d * (-1.0f / 32.0f));
    float p = hasY ? a * __bfloat162float(col[j]) : a;
    #pragma unroll
    for (int t = 0; t < 5; ++t) { s[t] += p; p *= d; }
  }
  #pragma unroll
  for (int t = 0; t < 5; ++t)
    for (int off = 1; off < 64; off <<= 1) s[t] += __shfl_xor(s[t], off);
  int wave = tid >> 6, lane = tid & 63;
  if (lane == 0)
    #pragma unroll
    for (int t = 0; t < 5; ++t) red[t][wave] = s[t];
  __syncthreads();
  if (tid == 0) {
    #pragma unroll
    for (int t = 0; t < 5; ++t) {
      float v = red[t][0] + red[t][1] + red[t][2] + red[t][3];
      if (hasY) Mt[t * 128 + c] = v; else Gt[t] = v;
    }
  }
}

__global__ void prior_vec(const float* __restrict__ impf, const float* __restrict__ Gt,
                          float* __restrict__ pvec) {
  int i = blockIdx.x * 256 + threadIdx.x;
  float d = impf[i];
  float a = __expf(d * d * (-1.0f / 32.0f));
  const float ct[5] = {1.0f, 1.0f / 16.0f, 1.0f / 512.0f, 1.0f / 24576.0f, 1.0f / 1572864.0f};
  float g[5];
  float p = a;
  #pragma unroll
  for (int t = 0; t < 5; ++t) { g[t] = ct[t] * p; p *= d; }
  float rs = 1.0f;  // + eye
  #pragma unroll
  for (int t = 0; t < 5; ++t) rs += g[t] * Gt[t];
  float inv = 1.0f / rs;
  #pragma unroll
  for (int t = 0; t < 5; ++t) pvec[i * 8 + t] = g[t] * inv;
  pvec[i * 8 + 5] = inv;
}

// ---------------- K=128 GEMM (MFMA): C = A @ Bt^T ----------------
// transC: writes C[n][m] (ldc = NN). Cr (optional): row-major copy C[m][n], ld = DD.
__launch_bounds__(256)
__global__ void gemm_k128(const bf16* __restrict__ A, const bf16* __restrict__ Bt,
                          bf16* __restrict__ C, int ldc, int transC, bf16* __restrict__ Cr) {
  __shared__ bf16 lA[128][136];
  __shared__ bf16 lB[64][136];
  int tid = threadIdx.x;
  long rowA0 = (long)blockIdx.y * 128;
  long rowB0 = (long)blockIdx.x * 64;
  for (int i = 0; i < 8; ++i) {
    int f = tid + i * 256;
    int r = f >> 4, kg = f & 15;
    *reinterpret_cast<uint4*>(&lA[r][kg * 8]) =
        *reinterpret_cast<const uint4*>(A + (rowA0 + r) * DD + kg * 8);
  }
  for (int i = 0; i < 4; ++i) {
    int f = tid + i * 256;
    int r = f >> 4, kg = f & 15;
    *reinterpret_cast<uint4*>(&lB[r][kg * 8]) =
        *reinterpret_cast<const uint4*>(Bt + (rowB0 + r) * DD + kg * 8);
  }
  __syncthreads();
  int wave = tid >> 6, lane = tid & 63;
  int wm = (wave >> 1) * 64;
  int wn = (wave & 1) * 32;
  int quad = lane >> 4, l16 = lane & 15;
  f32x4 acc[4][2];
  #pragma unroll
  for (int mi = 0; mi < 4; ++mi)
    #pragma unroll
    for (int ni = 0; ni < 2; ++ni) acc[mi][ni] = {0.f, 0.f, 0.f, 0.f};
  #pragma unroll
  for (int ks = 0; ks < 4; ++ks) {
    int kb = ks * 32 + quad * 8;
    bf16x8 af[4], bfr[2];
    #pragma unroll
    for (int mi = 0; mi < 4; ++mi)
      af[mi] = *reinterpret_cast<const bf16x8*>(&lA[wm + mi * 16 + l16][kb]);
    #pragma unroll
    for (int ni = 0; ni < 2; ++ni)
      bfr[ni] = *reinterpret_cast<const bf16x8*>(&lB[wn + ni * 16 + l16][kb]);
    #pragma unroll
    for (int mi = 0; mi < 4; ++mi)
      #pragma unroll
      for (int ni = 0; ni < 2; ++ni)
        acc[mi][ni] = __builtin_amdgcn_mfma_f32_16x16x32_bf16(af[mi], bfr[ni], acc[mi][ni], 0, 0, 0);
  }
  #pragma unroll
  for (int mi = 0; mi < 4; ++mi)
    #pragma unroll
    for (int ni = 0; ni < 2; ++ni)
      #pragma unroll
      for (int r = 0; r < 4; ++r) {
        long row = rowA0 + wm + mi * 16 + quad * 4 + r;
        long col = rowB0 + wn + ni * 16 + l16;
        bf16 v = __float2bfloat16(acc[mi][ni][r]);
        if (transC) C[col * (long)ldc + row] = v;
        else        C[row * (long)ldc + col] = v;
        if (Cr)     Cr[row * DD + col] = v;
      }
}

// ---------------- per-row exact top-k threshold + rowsum ----------------
// Radix binary search on order-preserving keys of bf16. Keys are stored
// PRE-SHIFTED <<16 so they span the full 32-bit range: the compiler was
// packing two u16 keys per VGPR (VGPR_Count tracked keys/2+8 across rounds)
// and paying an unpack VALU op on every compare. Full-width keys kill the
// packing; compare is then exactly one v_cmp (inline asm -> SGPR mask) plus
// scalar popcount/accumulate.
__launch_bounds__(256)
__global__ void topk_thresh(const bf16* __restrict__ S, unsigned short* __restrict__ kthr,
                            float* __restrict__ invRsF) {
  __shared__ int red[2][4];
  __shared__ float sred[4];
  int tid = threadIdx.x;
  int wave = tid >> 6, lane = tid & 63;
  long base = (long)blockIdx.x * NN;
  unsigned keys[32];
  #pragma unroll
  for (int i = 0; i < 4; ++i) {
    int f = tid + i * 256;
    uint4 v = *reinterpret_cast<const uint4*>(S + base + (long)f * 8);
    const unsigned short* p = reinterpret_cast<const unsigned short*>(&v);
    #pragma unroll
    for (int e = 0; e < 8; ++e) {
      unsigned short u = p[e];
      unsigned k16 = (u & 0x8000) ? (unsigned)(unsigned short)~u : (unsigned)(u | 0x8000);
      keys[i * 8 + e] = k16 << 16;          // full 32-bit range -> no u16 packing
    }
  }
  unsigned cur = 0;
  #pragma unroll
  for (int bit = 15; bit >= 0; --bit) {
    unsigned cand = cur | (1u << (16 + bit));
    int c = 0;
    #pragma unroll
    for (int i = 0; i < 32; ++i) {
      unsigned long long m;
      asm("v_cmp_ge_u32 %0, %1, %2" : "=s"(m) : "v"(keys[i]), "s"(cand));
      c += (int)__builtin_popcountll(m);
    }
    int buf = bit & 1;                 // double buffer -> one barrier per iteration
    if (lane == 0) red[buf][wave] = c; // c is wave-uniform
    __syncthreads();
    int tot = red[buf][0] + red[buf][1] + red[buf][2] + red[buf][3];
    if (tot >= KTOP) cur = cand;
  }
  float sum = 0.f;
  #pragma unroll
  for (int i = 0; i < 32; ++i) {
    unsigned k = keys[i];
    if (k >= cur) {
      unsigned k16 = k >> 16;
      unsigned short u = (k16 & 0x8000u) ? (unsigned short)(k16 ^ 0x8000u)
                                         : (unsigned short)~k16;
      sum += __uint_as_float(((unsigned int)u) << 16);
    }
  }
  for (int off = 1; off < 64; off <<= 1) sum += __shfl_xor(sum, off);
  if (lane == 0) sred[wave] = sum;
  __syncthreads();
  if (tid == 0) {
    invRsF[blockIdx.x] = 1.0f / (sred[0] + sred[1] + sred[2] + sred[3] + 1.0f);
    kthr[blockIdx.x] = (unsigned short)(cur >> 16);
  }
}

// ---------------- split-K masked AV GEMM: Pacc[s] = (mask(S) @ Y2) over k-slice s ----
__launch_bounds__(256)
__global__ void fused_av_partial(const bf16* __restrict__ S, const bf16* __restrict__ Yt2,
                                 const unsigned short* __restrict__ kthr,
                                 float* __restrict__ Pacc) {
  __shared__ bf16 lAf[32][72];
  __shared__ bf16 lY2[128][72];
  int tid = threadIdx.x;
  long row0 = (long)blockIdx.x * 32;
  long kbase = (long)blockIdx.y * KCH;
  int wave = tid >> 6, lane = tid & 63;
  int wm = (wave >> 1) * 16;   // 0 / 16
  int wn = (wave & 1) * 64;    // 0 / 64
  int quad = lane >> 4, l16 = lane & 15;
  int sr = tid >> 3, skg = tid & 7;          // staging coords: row, k-group
  int tk = kthr[row0 + sr];                  // per-thread row threshold key
  const bf16* srow = S + (row0 + sr) * (long)NN + kbase + skg * 8;
  f32x4 accF[4];
  #pragma unroll
  for (int ni = 0; ni < 4; ++ni) accF[ni] = {0.f, 0.f, 0.f, 0.f};
  for (int k0 = 0; k0 < KCH; k0 += 64) {
    __syncthreads();
    {
      uint4 v = *reinterpret_cast<const uint4*>(srow + k0);
      const unsigned short* p = reinterpret_cast<const unsigned short*>(&v);
      unsigned short m[8];
      #pragma unroll
      for (int e = 0; e < 8; ++e) {
        unsigned short u = p[e];
        int key = (u & 0x8000) ? (unsigned short)~u : (unsigned short)(u | 0x8000);
        m[e] = (key >= tk) ? u : (unsigned short)0;
      }
      *reinterpret_cast<uint4*>(&lAf[sr][skg * 8]) = *reinterpret_cast<const uint4*>(m);
    }
    for (int i = 0; i < 4; ++i) {       // 128 cols x 8 uint4
      int f = tid + i * 256;
      int c = f >> 3, kg = f & 7;
      *reinterpret_cast<uint4*>(&lY2[c][kg * 8]) =
          *reinterpret_cast<const uint4*>(Yt2 + (long)c * NN + kbase + k0 + kg * 8);
    }
    __syncthreads();
    #pragma unroll
    for (int ks = 0; ks < 2; ++ks) {
      int kb = ks * 32 + quad * 8;
      bf16x8 afm = *reinterpret_cast<const bf16x8*>(&lAf[wm + l16][kb]);
      #pragma unroll
      for (int ni = 0; ni < 4; ++ni) {
        bf16x8 b2 = *reinterpret_cast<const bf16x8*>(&lY2[wn + ni * 16 + l16][kb]);
        accF[ni] = __builtin_amdgcn_mfma_f32_16x16x32_bf16(afm, b2, accF[ni], 0, 0, 0);
      }
    }
  }
  float* out = Pacc + ((long)blockIdx.y * NN) * DD;
  #pragma unroll
  for (int ni = 0; ni < 4; ++ni)
    #pragma unroll
    for (int r = 0; r < 4; ++r) {
      long row = row0 + wm + quad * 4 + r;
      int col = wn + ni * 16 + l16;
      out[row * DD + col] = accF[ni][r];
    }
}

// ---------------- epilogue: reduce partials + prior + eye + leaky (+ optional final) ----
// If outf != nullptr: writes outf = v + hres*imp (final residual) instead of Xout.
__global__ void epilogue(const float* __restrict__ Pacc, const bf16* __restrict__ Yr1,
                         const bf16* __restrict__ Yr2, const float* __restrict__ pvec,
                         const float* __restrict__ Mt, const float* __restrict__ invRsF,
                         float* __restrict__ Xout, const float* __restrict__ hres,
                         const float* __restrict__ impf, float* __restrict__ outf) {
  int i = blockIdx.x * 256 + threadIdx.x;
  int row = i >> 7, col = i & 127;
  float acc = 0.f;
  #pragma unroll
  for (int s = 0; s < KSLICE; ++s) acc += Pacc[((long)s * NN + row) * DD + col];
  const float* pv = pvec + row * 8;
  float y1 = __bfloat162float(Yr1[i]);
  float y2 = __bfloat162float(Yr2[i]);
  float prior = pv[5] * y1 + pv[0] * Mt[col] + pv[1] * Mt[128 + col] + pv[2] * Mt[256 + col]
              + pv[3] * Mt[384 + col] + pv[4] * Mt[512 + col];
  float v = prior + invRsF[row] * (acc + y2);
  v = v > 0.f ? v : 0.01f * v;
  if (outf) outf[i] = v + hres[i] * impf[row];
  else      Xout[i] = v;
}

// ---------------- host ----------------

extern "C" void kernel_launch(void* const* d_in, const int* in_sizes, int n_in,
                              void* d_out, int out_size, void* d_ws, size_t ws_size,
                              hipStream_t stream) {
  const void* x_in   = d_in[0];
  const void* imp_in = d_in[1];
  const void* W1 = d_in[2];
  const void* W2 = d_in[3];
  float* out = (float*)d_out;

  char* ws = (char*)d_ws;
  size_t o = 0;
  auto alloc = [&](size_t bytes) { void* p = ws + o; o += (bytes + 511) & ~511ull; return p; };
  bf16*  Af   = (bf16*)alloc((size_t)NN * NN * 2);    // 134 MB raw similarity S
  float* Pacc = (float*)alloc((size_t)KSLICE * NN * DD * 4);  // 16 MB split-K partials
  float* xf0  = (float*)alloc((size_t)NN * DD * 4);
  float* xf1  = (float*)alloc((size_t)NN * DD * 4);
  bf16*  xnb  = (bf16*)alloc((size_t)NN * DD * 2);
  bf16*  xb   = (bf16*)alloc((size_t)NN * DD * 2);
  bf16*  Yt1  = (bf16*)alloc((size_t)NN * DD * 2);    // [128][8192] (x@W1)^T
  bf16*  Yt2  = (bf16*)alloc((size_t)NN * DD * 2);
  bf16*  Yr1  = (bf16*)alloc((size_t)NN * DD * 2);    // [8192][128] row-major copies
  bf16*  Yr2  = (bf16*)alloc((size_t)NN * DD * 2);
  bf16*  Wt1  = (bf16*)alloc((size_t)2 * DD * DD * 2);
  bf16*  Wt2  = (bf16*)alloc((size_t)2 * DD * DD * 2);
  float* impf = (float*)alloc((size_t)NN * 4);
  float* pvec = (float*)alloc((size_t)NN * 8 * 4);
  float* Mt   = (float*)alloc((size_t)5 * 128 * 4);
  float* Gt   = (float*)alloc((size_t)8 * 4);
  float* invRsF = (float*)alloc((size_t)NN * 4);
  unsigned short* kthr = (unsigned short*)alloc((size_t)NN * 2);
  int*   dflag  = (int*)alloc(64);
  (void)ws_size; (void)n_in; (void)in_sizes; (void)out_size;

  detect_dtype<<<1, 256, 0, stream>>>((const unsigned short*)x_in, dflag);
  prep<<<4101, 256, 0, stream>>>(x_in, imp_in, W1, W2, xf0, impf, Wt1, Wt2, dflag);

  float* xcur = xf0;
  for (int l = 0; l < 2; ++l) {
    float* xnxt = (l == 0) ? xf1 : xf0;
    rownorm<<<NN / 4, 256, 0, stream>>>(xcur, xnb, xb);
    gemm_k128<<<dim3(2, 64), 256, 0, stream>>>(xb, Wt1 + l * DD * DD, Yt1, NN, 1, Yr1);
    gemm_k128<<<dim3(2, 64), 256, 0, stream>>>(xb, Wt2 + l * DD * DD, Yt2, NN, 1, Yr2);
    prior_reduce<<<129, 256, 0, stream>>>(impf, Yt1, Mt, Gt);
    prior_vec<<<NN / 256, 256, 0, stream>>>(impf, Gt, pvec);
    gemm_k128<<<dim3(NN / 64, NN / 128), 256, 0, stream>>>(xnb, xnb, Af, NN, 0, nullptr);
    topk_thresh<<<NN, 256, 0, stream>>>(Af, kthr, invRsF);
    fused_av_partial<<<dim3(NN / 32, KSLICE), 256, 0, stream>>>(Af, Yt2, kthr, Pacc);
    if (l == 0)
      epilogue<<<NN * DD / 256, 256, 0, stream>>>(Pacc, Yr1, Yr2, pvec, Mt, invRsF,
                                                  xnxt, nullptr, nullptr, nullptr);
    else
      epilogue<<<NN * DD / 256, 256, 0, stream>>>(Pacc, Yr1, Yr2, pvec, Mt, invRsF,
                                                  nullptr, xf1, impf, out);
    xcur = xnxt;
  }
}

// Round 12
// 464.747 us; speedup vs baseline: 1.1121x; 1.0650x over previous
//
#include <hip/hip_runtime.h>
#include <hip/hip_bf16.h>

typedef __bf16 bf16x8 __attribute__((ext_vector_type(8)));
typedef float f32x4 __attribute__((ext_vector_type(4)));
typedef __hip_bfloat16 bf16;

static constexpr int NN = 8192;
static constexpr int DD = 128;
static constexpr int KTOP = 1638;   // int(0.2 * 8192)
static constexpr int KSLICE = 4;    // split-K factor for the AV GEMM
static constexpr int KCH = NN / KSLICE;

// ---------------- input dtype detection ----------------
__global__ void detect_dtype(const unsigned short* __restrict__ xin, int* __restrict__ flag) {
  __shared__ int cnt;
  if (threadIdx.x == 0) cnt = 0;
  __syncthreads();
  int c = 0;
  for (int i = threadIdx.x; i < 4096; i += 256) {
    int e = (xin[i] >> 7) & 0xFF;
    if (e >= 0x8A) ++c;
  }
  atomicAdd(&cnt, c);
  __syncthreads();
  if (threadIdx.x == 0) *flag = (cnt > 16) ? 1 : 0;
}

// ---------------- prep: cvt imp + transpose W (dual dtype), 5 blocks ----------------
__global__ void prep(const void* __restrict__ imp_in,
                     const void* __restrict__ W1, const void* __restrict__ W2,
                     float* __restrict__ impf,
                     bf16* __restrict__ Wt1, bf16* __restrict__ Wt2,
                     const int* __restrict__ flag) {
  int isf32 = *flag;
  int b = blockIdx.x;
  if (b == 0) {
    for (int i = threadIdx.x; i < NN; i += 256)
      impf[i] = isf32 ? ((const float*)imp_in)[i] : __bfloat162float(((const bf16*)imp_in)[i]);
  } else {
    int w = b - 1;                    // 0,1 -> W1 l=0,1 ; 2,3 -> W2 l=0,1
    const void* srcv = (w < 2 ? W1 : W2);
    bf16* dst = (w < 2 ? Wt1 : Wt2) + (w & 1) * DD * DD;
    int off = (w & 1) * DD * DD;
    for (int f = threadIdx.x; f < DD * DD; f += 256) {
      int n = f >> 7, k = f & 127;
      float v = isf32 ? ((const float*)srcv)[off + k * DD + n]
                      : __bfloat162float(((const bf16*)srcv)[off + k * DD + n]);
      dst[n * DD + k] = __float2bfloat16(v);
    }
  }
}

// per-row L2 normalize -> xnb (bf16) + plain bf16 cast -> xb.
// raw=1: src is the network input (dtype per flag); raw=0: src is an f32 buffer.
__global__ void rownorm(const void* __restrict__ src, const int* __restrict__ flag, int raw,
                        bf16* __restrict__ xnb, bf16* __restrict__ xb) {
  int wave = threadIdx.x >> 6;
  int lane = threadIdx.x & 63;
  int row = blockIdx.x * 4 + wave;
  float vx, vy;
  if (raw && *flag == 0) {            // raw bf16 input: unpack a pair
    unsigned u = ((const unsigned*)src)[(long)row * 64 + lane];
    vx = __uint_as_float(u << 16);
    vy = __uint_as_float(u & 0xFFFF0000u);
  } else {
    float2 v = ((const float2*)src)[(long)row * 64 + lane];
    vx = v.x; vy = v.y;
  }
  float s = vx * vx + vy * vy;
  for (int off = 1; off < 64; off <<= 1) s += __shfl_xor(s, off);
  float inv = 1.0f / (sqrtf(s) + 1e-8f);
  int c = lane * 2;
  xb[(long)row * DD + c]      = __float2bfloat16(vx);
  xb[(long)row * DD + c + 1]  = __float2bfloat16(vy);
  xnb[(long)row * DD + c]     = __float2bfloat16(vx * inv);
  xnb[(long)row * DD + c + 1] = __float2bfloat16(vy * inv);
}

// ---------------- rank-5 factorized Gaussian prior ----------------
// P_ij = exp(-(di-dj)^2/32) = a_i a_j exp(di dj/16); 5-term Taylor of exp(z), z<=1/16.
__launch_bounds__(256)
__global__ void prior_reduce(const float* __restrict__ impf, const bf16* __restrict__ Yt1,
                             float* __restrict__ Mt, float* __restrict__ Gt) {
  __shared__ float red[5][4];
  int c = blockIdx.x;
  int tid = threadIdx.x;
  float s[5] = {0.f, 0.f, 0.f, 0.f, 0.f};
  bool hasY = (c < 128);
  const bf16* col = Yt1 + (long)(hasY ? c : 0) * NN;
  for (int j = tid; j < NN; j += 256) {
    float d = impf[j];
    float a = __expf(d * d * (-1.0f / 32.0f));
    float p = hasY ? a * __bfloat162float(col[j]) : a;
    #pragma unroll
    for (int t = 0; t < 5; ++t) { s[t] += p; p *= d; }
  }
  #pragma unroll
  for (int t = 0; t < 5; ++t)
    for (int off = 1; off < 64; off <<= 1) s[t] += __shfl_xor(s[t], off);
  int wave = tid >> 6, lane = tid & 63;
  if (lane == 0)
    #pragma unroll
    for (int t = 0; t < 5; ++t) red[t][wave] = s[t];
  __syncthreads();
  if (tid == 0) {
    #pragma unroll
    for (int t = 0; t < 5; ++t) {
      float v = red[t][0] + red[t][1] + red[t][2] + red[t][3];
      if (hasY) Mt[t * 128 + c] = v; else Gt[t] = v;
    }
  }
}

__global__ void prior_vec(const float* __restrict__ impf, const float* __restrict__ Gt,
                          float* __restrict__ pvec) {
  int i = blockIdx.x * 256 + threadIdx.x;
  float d = impf[i];
  float a = __expf(d * d * (-1.0f / 32.0f));
  const float ct[5] = {1.0f, 1.0f / 16.0f, 1.0f / 512.0f, 1.0f / 24576.0f, 1.0f / 1572864.0f};
  float g[5];
  float p = a;
  #pragma unroll
  for (int t = 0; t < 5; ++t) { g[t] = ct[t] * p; p *= d; }
  float rs = 1.0f;  // + eye
  #pragma unroll
  for (int t = 0; t < 5; ++t) rs += g[t] * Gt[t];
  float inv = 1.0f / rs;
  #pragma unroll
  for (int t = 0; t < 5; ++t) pvec[i * 8 + t] = g[t] * inv;
  pvec[i * 8 + 5] = inv;
}

// ---------------- K=128 GEMM core (MFMA), shared by S-GEMM and Y-GEMMs ----------------
__device__ __forceinline__ void gemm_core(const bf16* __restrict__ A, const bf16* __restrict__ Bt,
                                          long rowA0, long rowB0, int tid,
                                          bf16* __restrict__ C, int ldc, int transC,
                                          bf16* __restrict__ Cr) {
  __shared__ bf16 lA[128][136];
  __shared__ bf16 lB[64][136];
  for (int i = 0; i < 8; ++i) {
    int f = tid + i * 256;
    int r = f >> 4, kg = f & 15;
    *reinterpret_cast<uint4*>(&lA[r][kg * 8]) =
        *reinterpret_cast<const uint4*>(A + (rowA0 + r) * DD + kg * 8);
  }
  for (int i = 0; i < 4; ++i) {
    int f = tid + i * 256;
    int r = f >> 4, kg = f & 15;
    *reinterpret_cast<uint4*>(&lB[r][kg * 8]) =
        *reinterpret_cast<const uint4*>(Bt + (rowB0 + r) * DD + kg * 8);
  }
  __syncthreads();
  int wave = tid >> 6, lane = tid & 63;
  int wm = (wave >> 1) * 64;
  int wn = (wave & 1) * 32;
  int quad = lane >> 4, l16 = lane & 15;
  f32x4 acc[4][2];
  #pragma unroll
  for (int mi = 0; mi < 4; ++mi)
    #pragma unroll
    for (int ni = 0; ni < 2; ++ni) acc[mi][ni] = {0.f, 0.f, 0.f, 0.f};
  #pragma unroll
  for (int ks = 0; ks < 4; ++ks) {
    int kb = ks * 32 + quad * 8;
    bf16x8 af[4], bfr[2];
    #pragma unroll
    for (int mi = 0; mi < 4; ++mi)
      af[mi] = *reinterpret_cast<const bf16x8*>(&lA[wm + mi * 16 + l16][kb]);
    #pragma unroll
    for (int ni = 0; ni < 2; ++ni)
      bfr[ni] = *reinterpret_cast<const bf16x8*>(&lB[wn + ni * 16 + l16][kb]);
    #pragma unroll
    for (int mi = 0; mi < 4; ++mi)
      #pragma unroll
      for (int ni = 0; ni < 2; ++ni)
        acc[mi][ni] = __builtin_amdgcn_mfma_f32_16x16x32_bf16(af[mi], bfr[ni], acc[mi][ni], 0, 0, 0);
  }
  #pragma unroll
  for (int mi = 0; mi < 4; ++mi)
    #pragma unroll
    for (int ni = 0; ni < 2; ++ni)
      #pragma unroll
      for (int r = 0; r < 4; ++r) {
        long row = rowA0 + wm + mi * 16 + quad * 4 + r;
        long col = rowB0 + wn + ni * 16 + l16;
        bf16 v = __float2bfloat16(acc[mi][ni][r]);
        if (transC) C[col * (long)ldc + row] = v;
        else        C[row * (long)ldc + col] = v;
        if (Cr)     Cr[row * DD + col] = v;
      }
}

// S = Xn @ Xn^T (row-major bf16, ldc = NN)
__launch_bounds__(256)
__global__ void gemm_s(const bf16* __restrict__ Xn, bf16* __restrict__ S) {
  gemm_core(Xn, Xn, (long)blockIdx.y * 128, (long)blockIdx.x * 64, threadIdx.x,
            S, NN, 0, nullptr);
}

// Both Y GEMMs in one launch: bx<2 -> W1 path, bx>=2 -> W2 path.
__launch_bounds__(256)
__global__ void gemm_y_dual(const bf16* __restrict__ xb,
                            const bf16* __restrict__ Wt1, const bf16* __restrict__ Wt2,
                            bf16* __restrict__ Yt1, bf16* __restrict__ Yt2,
                            bf16* __restrict__ Yr1, bf16* __restrict__ Yr2) {
  int sel = blockIdx.x >> 1;
  int bx = blockIdx.x & 1;
  gemm_core(xb, sel ? Wt2 : Wt1, (long)blockIdx.y * 128, (long)bx * 64, threadIdx.x,
            sel ? Yt2 : Yt1, NN, 1, sel ? Yr2 : Yr1);
}

// ---------------- per-row exact top-k threshold + rowsum ----------------
// Radix binary search on order-preserving keys (bf16 -> u16 key, stored <<16 so
// the compiler can't pack two per VGPR — R11 evidence). The per-candidate count
// is one compound asm block: 32x { v_cmp_ge_u32 -> sgpr mask; s_bcnt1; s_add }
// with two alternating mask regs (breaks the WAR chain). VALU = 32 v_cmp/round,
// popcount+accumulate on the scalar pipe. |S|<=1.02<2 lets bits 15,14 fuse into
// one round (bit14 outcome is the complement of bit15's).
#define K2(a, b) \
  "v_cmp_ge_u32 %[ma], %[k" #a "], %[cand]\n\t" \
  "v_cmp_ge_u32 %[mb], %[k" #b "], %[cand]\n\t" \
  "s_bcnt1_i32_b64 %[t], %[ma]\n\t" \
  "s_add_i32 %[c], %[c], %[t]\n\t" \
  "s_bcnt1_i32_b64 %[t], %[mb]\n\t" \
  "s_add_i32 %[c], %[c], %[t]\n\t"

__device__ __forceinline__ int count_ge32(const unsigned* k, unsigned cand) {
  int c, t;
  unsigned long long ma, mb;
  asm("s_mov_b32 %[c], 0\n\t"
      K2(0, 1) K2(2, 3) K2(4, 5) K2(6, 7)
      K2(8, 9) K2(10, 11) K2(12, 13) K2(14, 15)
      K2(16, 17) K2(18, 19) K2(20, 21) K2(22, 23)
      K2(24, 25) K2(26, 27) K2(28, 29) K2(30, 31)
      : [c]"=&s"(c), [t]"=&s"(t), [ma]"=&s"(ma), [mb]"=&s"(mb)
      : [k0]"v"(k[0]), [k1]"v"(k[1]), [k2]"v"(k[2]), [k3]"v"(k[3]),
        [k4]"v"(k[4]), [k5]"v"(k[5]), [k6]"v"(k[6]), [k7]"v"(k[7]),
        [k8]"v"(k[8]), [k9]"v"(k[9]), [k10]"v"(k[10]), [k11]"v"(k[11]),
        [k12]"v"(k[12]), [k13]"v"(k[13]), [k14]"v"(k[14]), [k15]"v"(k[15]),
        [k16]"v"(k[16]), [k17]"v"(k[17]), [k18]"v"(k[18]), [k19]"v"(k[19]),
        [k20]"v"(k[20]), [k21]"v"(k[21]), [k22]"v"(k[22]), [k23]"v"(k[23]),
        [k24]"v"(k[24]), [k25]"v"(k[25]), [k26]"v"(k[26]), [k27]"v"(k[27]),
        [k28]"v"(k[28]), [k29]"v"(k[29]), [k30]"v"(k[30]), [k31]"v"(k[31]),
        [cand]"s"(cand));
  return c;
}

__launch_bounds__(256)
__global__ void topk_thresh(const bf16* __restrict__ S, unsigned short* __restrict__ kthr,
                            float* __restrict__ invRsF) {
  __shared__ int red[2][4];
  __shared__ float sred[4];
  int tid = threadIdx.x;
  int wave = tid >> 6, lane = tid & 63;
  long base = (long)blockIdx.x * NN;
  unsigned keys[32];
  #pragma unroll
  for (int i = 0; i < 4; ++i) {
    int f = tid + i * 256;
    uint4 v = *reinterpret_cast<const uint4*>(S + base + (long)f * 8);
    const unsigned short* p = reinterpret_cast<const unsigned short*>(&v);
    #pragma unroll
    for (int e = 0; e < 8; ++e) {
      unsigned short u = p[e];
      unsigned k16 = (u & 0x8000) ? (unsigned)(unsigned short)~u : (unsigned)(u | 0x8000);
      keys[i * 8 + e] = k16 << 16;          // full 32-bit range -> no u16 packing
    }
  }
  int rnd = 0;
  auto block_total = [&](int c) -> int {
    int buf = rnd & 1;
    ++rnd;
    if (lane == 0) red[buf][wave] = c;      // c is wave-uniform
    __syncthreads();
    return __builtin_amdgcn_readfirstlane(red[buf][0] + red[buf][1] +
                                          red[buf][2] + red[buf][3]);
  };
  // fused bits 15+14: |S| < 2 so bit14 = !bit15
  int t15 = block_total(count_ge32(keys, 0x80000000u));
  unsigned cur = (t15 >= KTOP) ? 0x80000000u : 0x40000000u;
  #pragma unroll
  for (int bit = 13; bit >= 0; --bit) {
    unsigned cand = cur | (1u << (16 + bit));
    int tot = block_total(count_ge32(keys, cand));
    if (tot >= KTOP) cur = cand;
  }
  float sum = 0.f;
  #pragma unroll
  for (int i = 0; i < 32; ++i) {
    unsigned k = keys[i];
    if (k >= cur) {
      unsigned k16 = k >> 16;
      unsigned short u = (k16 & 0x8000u) ? (unsigned short)(k16 ^ 0x8000u)
                                         : (unsigned short)~k16;
      sum += __uint_as_float(((unsigned int)u) << 16);
    }
  }
  for (int off = 1; off < 64; off <<= 1) sum += __shfl_xor(sum, off);
  if (lane == 0) sred[wave] = sum;
  __syncthreads();
  if (tid == 0) {
    invRsF[blockIdx.x] = 1.0f / (sred[0] + sred[1] + sred[2] + sred[3] + 1.0f);
    kthr[blockIdx.x] = (unsigned short)(cur >> 16);
  }
}

// ---------------- split-K masked AV GEMM: Pacc[s] = (mask(S) @ Y2) over k-slice s ----
__launch_bounds__(256)
__global__ void fused_av_partial(const bf16* __restrict__ S, const bf16* __restrict__ Yt2,
                                 const unsigned short* __restrict__ kthr,
                                 float* __restrict__ Pacc) {
  __shared__ bf16 lAf[32][72];
  __shared__ bf16 lY2[128][72];
  int tid = threadIdx.x;
  long row0 = (long)blockIdx.x * 32;
  long kbase = (long)blockIdx.y * KCH;
  int wave = tid >> 6, lane = tid & 63;
  int wm = (wave >> 1) * 16;   // 0 / 16
  int wn = (wave & 1) * 64;    // 0 / 64
  int quad = lane >> 4, l16 = lane & 15;
  int sr = tid >> 3, skg = tid & 7;          // staging coords: row, k-group
  int tk = kthr[row0 + sr];                  // per-thread row threshold key
  const bf16* srow = S + (row0 + sr) * (long)NN + kbase + skg * 8;
  f32x4 accF[4];
  #pragma unroll
  for (int ni = 0; ni < 4; ++ni) accF[ni] = {0.f, 0.f, 0.f, 0.f};
  for (int k0 = 0; k0 < KCH; k0 += 64) {
    __syncthreads();
    {
      uint4 v = *reinterpret_cast<const uint4*>(srow + k0);
      const unsigned short* p = reinterpret_cast<const unsigned short*>(&v);
      unsigned short m[8];
      #pragma unroll
      for (int e = 0; e < 8; ++e) {
        unsigned short u = p[e];
        int key = (u & 0x8000) ? (unsigned short)~u : (unsigned short)(u | 0x8000);
        m[e] = (key >= tk) ? u : (unsigned short)0;
      }
      *reinterpret_cast<uint4*>(&lAf[sr][skg * 8]) = *reinterpret_cast<const uint4*>(m);
    }
    for (int i = 0; i < 4; ++i) {       // 128 cols x 8 uint4
      int f = tid + i * 256;
      int c = f >> 3, kg = f & 7;
      *reinterpret_cast<uint4*>(&lY2[c][kg * 8]) =
          *reinterpret_cast<const uint4*>(Yt2 + (long)c * NN + kbase + k0 + kg * 8);
    }
    __syncthreads();
    #pragma unroll
    for (int ks = 0; ks < 2; ++ks) {
      int kb = ks * 32 + quad * 8;
      bf16x8 afm = *reinterpret_cast<const bf16x8*>(&lAf[wm + l16][kb]);
      #pragma unroll
      for (int ni = 0; ni < 4; ++ni) {
        bf16x8 b2 = *reinterpret_cast<const bf16x8*>(&lY2[wn + ni * 16 + l16][kb]);
        accF[ni] = __builtin_amdgcn_mfma_f32_16x16x32_bf16(afm, b2, accF[ni], 0, 0, 0);
      }
    }
  }
  float* out = Pacc + ((long)blockIdx.y * NN) * DD;
  #pragma unroll
  for (int ni = 0; ni < 4; ++ni)
    #pragma unroll
    for (int r = 0; r < 4; ++r) {
      long row = row0 + wm + quad * 4 + r;
      int col = wn + ni * 16 + l16;
      out[row * DD + col] = accF[ni][r];
    }
}

// ---------------- epilogue: reduce partials + prior + eye + leaky (+ optional final) ----
__global__ void epilogue(const float* __restrict__ Pacc, const bf16* __restrict__ Yr1,
                         const bf16* __restrict__ Yr2, const float* __restrict__ pvec,
                         const float* __restrict__ Mt, const float* __restrict__ invRsF,
                         float* __restrict__ Xout, const float* __restrict__ hres,
                         const float* __restrict__ impf, float* __restrict__ outf) {
  int i = blockIdx.x * 256 + threadIdx.x;
  int row = i >> 7, col = i & 127;
  float acc = 0.f;
  #pragma unroll
  for (int s = 0; s < KSLICE; ++s) acc += Pacc[((long)s * NN + row) * DD + col];
  const float* pv = pvec + row * 8;
  float y1 = __bfloat162float(Yr1[i]);
  float y2 = __bfloat162float(Yr2[i]);
  float prior = pv[5] * y1 + pv[0] * Mt[col] + pv[1] * Mt[128 + col] + pv[2] * Mt[256 + col]
              + pv[3] * Mt[384 + col] + pv[4] * Mt[512 + col];
  float v = prior + invRsF[row] * (acc + y2);
  v = v > 0.f ? v : 0.01f * v;
  if (outf) outf[i] = v + hres[i] * impf[row];
  else      Xout[i] = v;
}

// ---------------- host ----------------

extern "C" void kernel_launch(void* const* d_in, const int* in_sizes, int n_in,
                              void* d_out, int out_size, void* d_ws, size_t ws_size,
                              hipStream_t stream) {
  const void* x_in   = d_in[0];
  const void* imp_in = d_in[1];
  const void* W1 = d_in[2];
  const void* W2 = d_in[3];
  float* out = (float*)d_out;

  char* ws = (char*)d_ws;
  size_t o = 0;
  auto alloc = [&](size_t bytes) { void* p = ws + o; o += (bytes + 511) & ~511ull; return p; };
  bf16*  Af   = (bf16*)alloc((size_t)NN * NN * 2);    // 134 MB raw similarity S
  float* Pacc = (float*)alloc((size_t)KSLICE * NN * DD * 4);  // 16 MB split-K partials
  float* xf1  = (float*)alloc((size_t)NN * DD * 4);   // layer-0 output (= h for residual)
  bf16*  xnb  = (bf16*)alloc((size_t)NN * DD * 2);
  bf16*  xb   = (bf16*)alloc((size_t)NN * DD * 2);
  bf16*  Yt1  = (bf16*)alloc((size_t)NN * DD * 2);    // [128][8192] (x@W1)^T
  bf16*  Yt2  = (bf16*)alloc((size_t)NN * DD * 2);
  bf16*  Yr1  = (bf16*)alloc((size_t)NN * DD * 2);    // [8192][128] row-major copies
  bf16*  Yr2  = (bf16*)alloc((size_t)NN * DD * 2);
  bf16*  Wt1  = (bf16*)alloc((size_t)2 * DD * DD * 2);
  bf16*  Wt2  = (bf16*)alloc((size_t)2 * DD * DD * 2);
  float* impf = (float*)alloc((size_t)NN * 4);
  float* pvec = (float*)alloc((size_t)NN * 8 * 4);
  float* Mt   = (float*)alloc((size_t)5 * 128 * 4);
  float* Gt   = (float*)alloc((size_t)8 * 4);
  float* invRsF = (float*)alloc((size_t)NN * 4);
  unsigned short* kthr = (unsigned short*)alloc((size_t)NN * 2);
  int*   dflag  = (int*)alloc(64);
  (void)ws_size; (void)n_in; (void)in_sizes; (void)out_size;

  detect_dtype<<<1, 256, 0, stream>>>((const unsigned short*)x_in, dflag);
  prep<<<5, 256, 0, stream>>>(imp_in, W1, W2, impf, Wt1, Wt2, dflag);

  for (int l = 0; l < 2; ++l) {
    rownorm<<<NN / 4, 256, 0, stream>>>(l ? (const void*)xf1 : x_in, dflag, l ? 0 : 1, xnb, xb);
    gemm_y_dual<<<dim3(4, 64), 256, 0, stream>>>(xb, Wt1 + l * DD * DD, Wt2 + l * DD * DD,
                                                 Yt1, Yt2, Yr1, Yr2);
    prior_reduce<<<129, 256, 0, stream>>>(impf, Yt1, Mt, Gt);
    prior_vec<<<NN / 256, 256, 0, stream>>>(impf, Gt, pvec);
    gemm_s<<<dim3(NN / 64, NN / 128), 256, 0, stream>>>(xnb, Af);
    topk_thresh<<<NN, 256, 0, stream>>>(Af, kthr, invRsF);
    fused_av_partial<<<dim3(NN / 32, KSLICE), 256, 0, stream>>>(Af, Yt2, kthr, Pacc);
    if (l == 0)
      epilogue<<<NN * DD / 256, 256, 0, stream>>>(Pacc, Yr1, Yr2, pvec, Mt, invRsF,
                                                  xf1, nullptr, nullptr, nullptr);
    else
      epilogue<<<NN * DD / 256, 256, 0, stream>>>(Pacc, Yr1, Yr2, pvec, Mt, invRsF,
                                                  nullptr, xf1, impf, out);
  }
}